// Round 12
// baseline (421.182 us; speedup 1.0000x reference)
//
#include <hip/hip_runtime.h>
#include <hip/hip_bf16.h>

// ---------------------------------------------------------------------------
// GraphTransformerBlock: TransformerConv(H=2, C=128) + skip + LN + FFN + LN
// R21: R20 (347.6us best; attn at fp8-gather roofline, 53us) + GEMM K-loop
// moves to BK=64: two 32-K chunks staged per barrier pair (chunk-major LDS,
// R12-verified indexing) -> HALVES the vmcnt(0)-drain events that dominate
// the latency-bound GEMMs (R11: MfmaUtil 5%, 72% stall; __syncthreads drains
// the VMEM queue so prefetch can't help — only fewer barriers can).
// LDS 15->30.7KB: still VGPR-capped (~4 blocks/CU), unlike R12's 80KB crash.
// Dead template paths deleted (BM=128, AF32 — unused since R19/R13).
// attn/cvt_kv/prep/CSR unchanged (R20-verified).
// O1 row [1024]: q 0-255 | kv-interleaved 256-767 | skip 768-895 | P 896-959
// ---------------------------------------------------------------------------

typedef __attribute__((ext_vector_type(8))) short bf16x8;
typedef __attribute__((ext_vector_type(8))) unsigned short u16x8;
typedef __attribute__((ext_vector_type(4))) float f32x4;
typedef __attribute__((ext_vector_type(2))) float f32x2;

__device__ __forceinline__ float bf2f(unsigned short u) {
    union { float f; unsigned u32; } x; x.u32 = ((unsigned)u) << 16; return x.f;
}
__device__ __forceinline__ unsigned short f2bf(float f) {
    unsigned u = __float_as_uint(f);
    return (unsigned short)((u + 0x7FFFu + ((u >> 16) & 1u)) >> 16);
}

// ---------------- x -> bf16, one shot ---------------------------------------
__global__ __launch_bounds__(256)
void cast_x(const float* __restrict__ x, unsigned short* __restrict__ xh,
            int total8) {
    int t = blockIdx.x * 256 + threadIdx.x;
    if (t >= total8) return;
    const float4 a = *(const float4*)(x + (size_t)t * 8);
    const float4 b = *(const float4*)(x + (size_t)t * 8 + 4);
    u16x8 v;
    v[0] = f2bf(a.x); v[1] = f2bf(a.y); v[2] = f2bf(a.z); v[3] = f2bf(a.w);
    v[4] = f2bf(b.x); v[5] = f2bf(b.y); v[6] = f2bf(b.z); v[7] = f2bf(b.w);
    *(u16x8*)(xh + (size_t)t * 8) = v;
}

// ---------------- O1 KV slice -> fp8 e4m3 packed buffer ---------------------
// kv8[row][512]: byte c = fp8(O1[row][256+c]). 8 values per thread,
// coalesced 16B read / 8B write. total = N*64 groups.
__global__ __launch_bounds__(256)
void cvt_kv(const unsigned short* __restrict__ O1,
            unsigned char* __restrict__ kv8, int total) {
    int t = blockIdx.x * 256 + threadIdx.x;
    if (t >= total) return;
    int row = t >> 6;
    int col = (t & 63) * 8;
    u16x8 v = *(const u16x8*)(O1 + (size_t)row * 1024 + 256 + col);
    int lo = 0, hi = 0;
    lo = __builtin_amdgcn_cvt_pk_fp8_f32(bf2f(v[0]), bf2f(v[1]), lo, false);
    lo = __builtin_amdgcn_cvt_pk_fp8_f32(bf2f(v[2]), bf2f(v[3]), lo, true);
    hi = __builtin_amdgcn_cvt_pk_fp8_f32(bf2f(v[4]), bf2f(v[5]), hi, false);
    hi = __builtin_amdgcn_cvt_pk_fp8_f32(bf2f(v[6]), bf2f(v[7]), hi, true);
    *(int2*)(kv8 + (size_t)row * 512 + col) = make_int2(lo, hi);
}

// ---------------- bf16 MFMA GEMM + optional fused LN epilogue ---------------
// C[M,OC] = act(A[M,K] @ W[OC,K]^T + bias), tile 64 x 128, bf16 A.
// K-loop: BK=64 passes — two 32-K chunks per barrier pair, chunk-major LDS
// (As[2][64][40], Bs[2][128][40]; pitch 40 kills conflicts).
// EPI=0: plain store. EPI=1 (grid.x==1, OC=128): t = acc+add0+add1+bf16(skip);
// out = LN(t) -> bf16. EPI=2: f = acc+bias; t = bf16(hprev)+f; LN -> f32.
template<int ACT, int EPI, int OUT_BF16>
__global__ __launch_bounds__(256)
void gemm_fused(const unsigned short* __restrict__ Ah, int lda,
                const unsigned short* __restrict__ W, int ldw,
                const float* __restrict__ bias,
                void* __restrict__ outp, int ldo, int M, int K,
                const float* __restrict__ add0, const float* __restrict__ add1,
                const unsigned short* __restrict__ skipp, int skip_ld,
                const unsigned short* __restrict__ hprev,
                const float* __restrict__ lng, const float* __restrict__ lnb) {
    constexpr int CHA = 64 * 40;              // shorts per A chunk
    constexpr int CHB = 128 * 40;             // shorts per B chunk
    __shared__ unsigned short As[2 * CHA];
    __shared__ unsigned short Bs[2 * CHB];
    const int tid = threadIdx.x;
    const int wave = tid >> 6, lane = tid & 63;

    // XCD-chunked bijective block swizzle (m204): verified R11
    // (projection FETCH 100MB -> 14MB).
    int row0, col0;
    {
        const int gx   = gridDim.x;
        const int nwg  = gx * gridDim.y;
        const int orig = blockIdx.y * gx + blockIdx.x;
        const int q8   = nwg >> 3, r8 = nwg & 7;
        const int xcd  = orig & 7, sub = orig >> 3;
        const int swz  = (xcd < r8 ? xcd * (q8 + 1)
                                   : r8 * (q8 + 1) + (xcd - r8) * q8) + sub;
        row0 = (swz / gx) * 64;
        col0 = (swz % gx) * 128;
    }

    const int srow = tid >> 2;                 // 0..63
    const int skg  = (tid & 3) * 8;
    int r0 = row0 + srow;      if (r0 >= M) r0 = 0;
    const int b0 = col0 + srow, b1 = col0 + srow + 64;

    f32x4 acc[8];
    const f32x4 z4 = {0.f, 0.f, 0.f, 0.f};
    #pragma unroll
    for (int j = 0; j < 8; j++) acc[j] = z4;

    const int mrow = wave * 16 + (lane & 15);
    const int kq = (lane >> 4) * 8;
    const int lgrp = lane & 15;

    for (int ps = 0; ps < K; ps += 64) {
        // ---- load both chunks' fragments into registers ----
        u16x8 sa[2]; float4 sw0[2], sw1[2];
        #pragma unroll
        for (int c = 0; c < 2; c++) {
            const int kt = ps + c * 32;
            sa[c]  = *(const u16x8*)(Ah + (size_t)r0 * lda + kt + skg);
            sw0[c] = *(const float4*)(W + (size_t)b0 * ldw + kt + skg);
            sw1[c] = *(const float4*)(W + (size_t)b1 * ldw + kt + skg);
        }
        // barrier 1: all waves done reading previous pass's LDS
        __syncthreads();
        #pragma unroll
        for (int c = 0; c < 2; c++) {
            *(u16x8*)&As[c * CHA + srow * 40 + skg]         = sa[c];
            *(float4*)&Bs[c * CHB + srow * 40 + skg]        = sw0[c];
            *(float4*)&Bs[c * CHB + (srow + 64) * 40 + skg] = sw1[c];
        }
        // barrier 2: writes visible before reads
        __syncthreads();
        #pragma unroll
        for (int c = 0; c < 2; c++) {
            bf16x8 af0 = *(const bf16x8*)&As[c * CHA + mrow * 40 + kq];
            bf16x8 bfr[8];
            #pragma unroll
            for (int j = 0; j < 8; j++)
                bfr[j] = *(const bf16x8*)&Bs[c * CHB + (j * 16 + lgrp) * 40 + kq];
            #pragma unroll
            for (int j = 0; j < 8; j++)
                acc[j] = __builtin_amdgcn_mfma_f32_16x16x32_bf16(af0, bfr[j], acc[j], 0, 0, 0);
        }
    }

    // C/D layout: col = lane&15, row = (lane>>4)*4 + reg
    if (EPI == 0) {
        const int orow0 = row0 + wave * 16 + ((lane >> 4) << 2);
        const int ocol0 = col0 + lgrp;
        #pragma unroll
        for (int r = 0; r < 4; r++) {
            int row = orow0 + r;
            if (row >= M) continue;
            #pragma unroll
            for (int j = 0; j < 8; j++) {
                int col = ocol0 + j * 16;
                float v = acc[j][r] + (bias ? bias[col] : 0.f);
                if (ACT == 1) v = (v > 0.f) ? v : 0.01f * v;
                if (OUT_BF16) ((unsigned short*)outp)[(size_t)row * ldo + col] = f2bf(v);
                else          ((float*)outp)[(size_t)row * ldo + col] = v;
            }
        }
    } else {
        #pragma unroll
        for (int r = 0; r < 4; r++) {
            int row = row0 + wave * 16 + ((lane >> 4) << 2) + r;
            if (row >= M) continue;
            float t[8];
            #pragma unroll
            for (int j = 0; j < 8; j++) {
                int col = lgrp + j * 16;
                float v = acc[j][r];
                if (EPI == 1) {
                    v += add0[(size_t)row * 128 + col] + add1[(size_t)row * 128 + col]
                       + bf2f(skipp[(size_t)row * skip_ld + col]);
                } else {
                    v += bias[col];
                    v += bf2f(hprev[(size_t)row * 128 + col]);
                }
                t[j] = v;
            }
            float s = 0.f;
            #pragma unroll
            for (int j = 0; j < 8; j++) s += t[j];
            #pragma unroll
            for (int off = 8; off >= 1; off >>= 1) s += __shfl_xor(s, off);
            float mu = s * (1.f / 128.f);
            float q = 0.f;
            #pragma unroll
            for (int j = 0; j < 8; j++) { float d = t[j] - mu; q += d * d; }
            #pragma unroll
            for (int off = 8; off >= 1; off >>= 1) q += __shfl_xor(q, off);
            float rs = rsqrtf(q * (1.f / 128.f) + 1e-5f);
            #pragma unroll
            for (int j = 0; j < 8; j++) {
                int col = lgrp + j * 16;
                float o = (t[j] - mu) * rs * lng[col] + lnb[col];
                if (EPI == 1) ((unsigned short*)outp)[(size_t)row * ldo + col] = f2bf(o);
                else          ((float*)outp)[(size_t)row * ldo + col] = o;
            }
        }
    }
}

// ---------------- prep: weights + deg_count, one dispatch -------------------
#define WPREP 205824
__global__ void prep_all(const float* __restrict__ Wq, const float* __restrict__ bq,
                         const float* __restrict__ Wk, const float* __restrict__ bk,
                         const float* __restrict__ Wv, const float* __restrict__ bv,
                         const float* __restrict__ We, const float* __restrict__ Wsk,
                         const float* __restrict__ bsk,
                         const float* __restrict__ W1, const float* __restrict__ W2,
                         unsigned short* __restrict__ Wcat, float* __restrict__ bcat,
                         unsigned short* __restrict__ W1h, unsigned short* __restrict__ W2h,
                         unsigned short* __restrict__ Wec2,
                         const int* __restrict__ dst, int* __restrict__ deg, int E) {
    int k = blockIdx.x * 256 + threadIdx.x;
    if (k >= WPREP) {                       // deg count segment
        int e = k - WPREP;
        if (e < E) atomicAdd(&deg[dst[e]], 1);
        return;
    }
    if (k < 131072) {                       // Wcat [1024][128]
        int oc = k >> 7, r = k & 127;
        float v;
        if (oc < 256) v = Wq[(size_t)oc * 128 + r];
        else if (oc < 768) {
            int rr = oc - 256, g = rr >> 3, p = rr & 7;
            int h = g >> 5, ch = h * 128 + (g & 31) * 4 + (p & 3);
            v = (p < 4) ? Wk[(size_t)ch * 128 + r] : Wv[(size_t)ch * 128 + r];
        } else if (oc < 896) v = Wsk[(size_t)(oc - 768) * 128 + r];
        else if (oc < 960) {
            int qd = oc - 896, h = qd >> 5, t = qd & 31;
            float s = 0.f;
            for (int c = 0; c < 128; c++)
                s += Wq[(size_t)(h*128 + c) * 128 + r] * We[(size_t)(h*128 + c) * 32 + t];
            v = s;
        } else v = 0.f;
        Wcat[k] = f2bf(v);
    } else if (k < 132096) {                // bcat [1024]
        int oc = k - 131072;
        float v;
        if (oc < 256) v = bq[oc];
        else if (oc < 768) {
            int rr = oc - 256, g = rr >> 3, p = rr & 7;
            int ch = (g >> 5) * 128 + (g & 31) * 4 + (p & 3);
            v = (p < 4) ? bk[ch] : bv[ch];
        } else if (oc < 896) v = bsk[oc - 768];
        else if (oc < 960) {
            int qd = oc - 896, h = qd >> 5, t = qd & 31;
            float s = 0.f;
            for (int c = 0; c < 128; c++)
                s += bq[h*128 + c] * We[(size_t)(h*128 + c) * 32 + t];
            v = s;
        } else v = 0.f;
        bcat[oc] = v;
    } else if (k < 164864) {                // W1h
        int j = k - 132096;
        W1h[j] = f2bf(W1[j]);
    } else if (k < 197632) {                // W2h
        int j = k - 164864;
        W2h[j] = f2bf(W2[j]);
    } else {                                // Wec2 [128][64], 0.5 head-mean folded
        int j = k - 197632;
        int c = j >> 6, tt = j & 63, h = tt >> 5, t = tt & 31;
        Wec2[j] = f2bf(0.5f * We[(size_t)(h * 128 + c) * 32 + t]);
    }
}

// ---------------- CSR scan --------------------------------------------------
__global__ __launch_bounds__(256)
void scan_block(const int* __restrict__ deg, int* __restrict__ tmp,
                int* __restrict__ bsum, int n) {
    __shared__ int lds[256];
    int i = blockIdx.x * 256 + threadIdx.x;
    int v = (i < n) ? deg[i] : 0;
    lds[threadIdx.x] = v;
    __syncthreads();
    #pragma unroll
    for (int off = 1; off < 256; off <<= 1) {
        int t = (threadIdx.x >= off) ? lds[threadIdx.x - off] : 0;
        __syncthreads();
        lds[threadIdx.x] += t;
        __syncthreads();
    }
    if (i < n) tmp[i] = lds[threadIdx.x];
    if (threadIdx.x == 255) bsum[blockIdx.x] = lds[255];
}
__global__ __launch_bounds__(1024)
void scan_bsum(int* __restrict__ bsum, int nb) {
    __shared__ int lds[1024];
    int v = (threadIdx.x < nb) ? bsum[threadIdx.x] : 0;
    lds[threadIdx.x] = v;
    __syncthreads();
    #pragma unroll
    for (int off = 1; off < 1024; off <<= 1) {
        int t = (threadIdx.x >= off) ? lds[threadIdx.x - off] : 0;
        __syncthreads();
        lds[threadIdx.x] += t;
        __syncthreads();
    }
    if (threadIdx.x < nb) bsum[threadIdx.x] = lds[threadIdx.x] - v;  // exclusive
}
// row_start(d) = (d==0) ? 0 : tmp[d-1] + sbx[(d-1)>>8]
__global__ void csr_fill(const int* __restrict__ src, const int* __restrict__ dst,
                         const int* __restrict__ tmp, const int* __restrict__ sbx,
                         int* __restrict__ cnt, int2* __restrict__ eid2, int E) {
    int e = blockIdx.x * blockDim.x + threadIdx.x;
    if (e < E) {
        int d = dst[e];
        int start = (d == 0) ? 0 : (tmp[d - 1] + sbx[(d - 1) >> 8]);
        int pos = start + atomicAdd(&cnt[d], 1);
        eid2[pos] = make_int2(e, src[e]);
    }
}

// ---------------- fused attention: 1 wave/block, 4-edge ping-pong, fp8 KV ---
// Pipeline invariant at loop top: kvX holds data for group at j; idx holds
// indices for group at j+4. Every exp() slot guarded by (jb+i<jend); OOB
// slots load nothing (sentinel zeros, fp8 0x00 == 0.0f) and contribute w=0.
// Epilogue: per-head normalize, head-mean via shfl_xor(32) -> agg[N,128].

#define ATTN_LOADG(kv, ea, idx)                                               \
    _Pragma("unroll")                                                         \
    for (int i = 0; i < 4; i++) {                                             \
        if (idx[i].y >= 0) {                                                  \
            kv[i] = *(const uint2*)(KV8 + (size_t)idx[i].y * 512 + lane * 8); \
            ea[i] = EA[(size_t)idx[i].x * 32 + hl];                           \
        } else { kv[i] = zkv; ea[i] = 0.f; }                                  \
    }

#define ATTN_FETCHIDX(idx, base)                                              \
    _Pragma("unroll")                                                         \
    for (int i = 0; i < 4; i++)                                               \
        idx[i] = (base + i < jend) ? eid2[base + i] : make_int2(0, -1);

#define ATTN_COMPUTE(kv, ea, jb)                                              \
    {                                                                         \
        float d_[4];                                                          \
        f32x2 vlo_[4], vhi_[4];                                               \
        _Pragma("unroll")                                                     \
        for (int i = 0; i < 4; i++) {                                         \
            f32x2 k01 = __builtin_amdgcn_cvt_pk_f32_fp8((int)kv[i].x, false); \
            f32x2 k23 = __builtin_amdgcn_cvt_pk_f32_fp8((int)kv[i].x, true);  \
            vlo_[i]   = __builtin_amdgcn_cvt_pk_f32_fp8((int)kv[i].y, false); \
            vhi_[i]   = __builtin_amdgcn_cvt_pk_f32_fp8((int)kv[i].y, true);  \
            d_[i] = qv.x*k01.x + qv.y*k01.y + qv.z*k23.x + qv.w*k23.y         \
                  + pd*ea[i];                                                 \
        }                                                                     \
        _Pragma("unroll")                                                     \
        for (int off = 16; off >= 1; off >>= 1) {                             \
            _Pragma("unroll")                                                 \
            for (int i = 0; i < 4; i++) d_[i] += __shfl_xor(d_[i], off);      \
        }                                                                     \
        _Pragma("unroll")                                                     \
        for (int i = 0; i < 4; i++) {                                         \
            float wv = ((jb) + i < jend) ? __expf(d_[i] * inv) : 0.f;         \
            l += wv;                                                          \
            acc.x += wv * vlo_[i].x;                                          \
            acc.y += wv * vlo_[i].y;                                          \
            acc.z += wv * vhi_[i].x;                                          \
            acc.w += wv * vhi_[i].y;                                          \
            wacc  += wv * ea[i];                                              \
        }                                                                     \
    }

__global__ __launch_bounds__(64)
void fused_attn(const unsigned short* __restrict__ O1,
                const unsigned char* __restrict__ KV8,
                const float* __restrict__ EA,
                const int* __restrict__ tmp, const int* __restrict__ sbx,
                const int2* __restrict__ eid2,
                float* __restrict__ agg, unsigned short* __restrict__ weab, int N) {
    const int node = blockIdx.x;
    const int lane = threadIdx.x;
    const int hl = lane & 31;
    const int choff = (lane >> 5) * 128 + (hl << 2);
    const float inv = 0.08838834764831845f;  // 1/sqrt(128)

    ushort4 q4 = *(const ushort4*)(O1 + (size_t)node * 1024 + choff);
    float4 qv = make_float4(bf2f(q4.x), bf2f(q4.y), bf2f(q4.z), bf2f(q4.w));
    float pd = bf2f(O1[(size_t)node * 1024 + 896 + lane]);

    const int j0 = (node == 0) ? 0 : (tmp[node - 1] + sbx[(node - 1) >> 8]);
    const int jend = tmp[node] + sbx[node >> 8];

    float l = 0.f, wacc = 0.f;
    float4 acc = make_float4(0.f, 0.f, 0.f, 0.f);

    const uint2 zkv = make_uint2(0u, 0u);
    uint2 kvA[4], kvB[4];
    float eaA[4], eaB[4];
    int2 idx[4];

    int j = j0;
    if (j < jend) {
        // group 0 data -> A (inline indices)
        #pragma unroll
        for (int i = 0; i < 4; i++) {
            if (j + i < jend) {
                int2 es = eid2[j + i];
                kvA[i] = *(const uint2*)(KV8 + (size_t)es.y * 512 + lane * 8);
                eaA[i] = EA[(size_t)es.x * 32 + hl];
            } else { kvA[i] = zkv; eaA[i] = 0.f; }
        }
        // indices for group 1
        ATTN_FETCHIDX(idx, j + 4);

        while (j < jend) {
            // phase A: data j+4 -> B, indices j+8, compute A(j)
            ATTN_LOADG(kvB, eaB, idx);
            ATTN_FETCHIDX(idx, j + 8);
            ATTN_COMPUTE(kvA, eaA, j);
            j += 4;
            if (j >= jend) break;

            // phase B: data j+4 -> A, indices j+8, compute B(j)
            ATTN_LOADG(kvA, eaA, idx);
            ATTN_FETCHIDX(idx, j + 8);
            ATTN_COMPUTE(kvB, eaB, j);
            j += 4;
        }
    }

    float r = 1.f / (l + 1e-16f);
    weab[(size_t)node * 64 + lane] = f2bf(wacc * r);
    float ax = acc.x * r, ay = acc.y * r, az = acc.z * r, aw = acc.w * r;
    float mx = 0.5f * (ax + __shfl_xor(ax, 32));
    float my = 0.5f * (ay + __shfl_xor(ay, 32));
    float mz = 0.5f * (az + __shfl_xor(az, 32));
    float mw = 0.5f * (aw + __shfl_xor(aw, 32));
    if (lane < 32)
        *(float4*)(agg + (size_t)node * 128 + hl * 4) = make_float4(mx, my, mz, mw);
}

// ---------------------------------------------------------------------------
extern "C" void kernel_launch(void* const* d_in, const int* in_sizes, int n_in,
                              void* d_out, int out_size, void* d_ws, size_t ws_size,
                              hipStream_t stream) {
    const float* x    = (const float*)d_in[0];
    const int*   ei   = (const int*)d_in[1];
    const float* ea   = (const float*)d_in[2];
    const float* Wq   = (const float*)d_in[3];
    const float* bq   = (const float*)d_in[4];
    const float* Wk   = (const float*)d_in[5];
    const float* bk   = (const float*)d_in[6];
    const float* Wv   = (const float*)d_in[7];
    const float* bv   = (const float*)d_in[8];
    const float* We   = (const float*)d_in[9];
    const float* Wsk  = (const float*)d_in[10];
    const float* bsk  = (const float*)d_in[11];
    const float* g1   = (const float*)d_in[12];
    const float* b1l  = (const float*)d_in[13];
    const float* W1   = (const float*)d_in[14];
    const float* b1f  = (const float*)d_in[15];
    const float* W2   = (const float*)d_in[16];
    const float* b2f  = (const float*)d_in[17];
    const float* g2   = (const float*)d_in[18];
    const float* b2l  = (const float*)d_in[19];
    float* out = (float*)d_out;

    const int N = in_sizes[0] / 128;
    const int E = in_sizes[2] / 32;
    const int* src = ei;
    const int* dst = ei + E;

    char* w = (char*)d_ws;
    unsigned short* O1   = (unsigned short*)w;  w += (size_t)N * 2048;  // [N,1024] bf16
    float* agg           = (float*)w;           w += (size_t)N * 512;   // [N,128] f32
    unsigned short* weab = (unsigned short*)w;  w += (size_t)N * 128;   // [N,64] bf16
    unsigned short* hb   = (unsigned short*)w;  w += (size_t)N * 256;   // [N,128] bf16
    unsigned char* kv8   = (unsigned char*)w;   w += (size_t)N * 512;   // [N,512] fp8
    unsigned short* Wcat = (unsigned short*)w;  w += 1024 * 128 * 2;
    float* bcat          = (float*)w;           w += 1024 * 4;
    unsigned short* W1h  = (unsigned short*)w;  w += 256 * 128 * 2;
    unsigned short* W2h  = (unsigned short*)w;  w += 128 * 256 * 2;
    unsigned short* Wec2 = (unsigned short*)w;  w += 128 * 64 * 2;
    int2* eid2           = (int2*)w;            w += (size_t)E * 8;
    int* deg  = (int*)w;            // [N] — zeroed by memset (with cnt)
    int* cnt  = deg + N;            // [N]
    int* tmp  = cnt + N;            // [N]
    int* bsum = tmp + N;            // <=1024

    // aliases of agg (timeline-disjoint):
    //   xh  bf16 [N,128] (N*256 B) — written by cast_x, read by projection;
    //                                 dead once fused_attn writes agg.
    //   mid bf16 [N,256] (N*512 B) — written by FFN1 after econ consumed agg.
    unsigned short* xh  = (unsigned short*)agg;
    unsigned short* mid = (unsigned short*)agg;

    const int gy64  = (N + 63) / 64;
    const int nb = (N + 255) / 256;

    // ---- zero deg+cnt (memset node), x->bf16, prep weights + deg_count ----
    hipMemsetAsync(deg, 0, (size_t)2 * N * 4, stream);
    const int total8 = (N * 128) / 8;
    cast_x<<<(total8 + 255) / 256, 256, 0, stream>>>(x, xh, total8);
    prep_all<<<(WPREP + E + 255) / 256, 256, 0, stream>>>(
        Wq, bq, Wk, bk, Wv, bv, We, Wsk, bsk, W1, W2,
        Wcat, bcat, W1h, W2h, Wec2, dst, deg, E);

    // ---- projection GEMM (bf16 A): O1 = xh @ Wcat^T + bcat ----
    gemm_fused<0,0,1><<<dim3(8, gy64), 256, 0, stream>>>(
        xh, 128, Wcat, 128, bcat, O1, 1024, N, 128,
        nullptr, nullptr, nullptr, 0, nullptr, nullptr, nullptr);

    // ---- KV slice -> fp8 packed buffer ----
    const int totkv = N * 64;
    cvt_kv<<<(totkv + 255) / 256, 256, 0, stream>>>(O1, kv8, totkv);

    // ---- CSR: scan + fill ----
    scan_block<<<nb, 256, 0, stream>>>(deg, tmp, bsum, N);
    scan_bsum<<<1, 1024, 0, stream>>>(bsum, nb);
    csr_fill<<<(E + 255)/256, 256, 0, stream>>>(src, dst, tmp, bsum, cnt, eid2, E);

    // ---- attention (1 wave/block, 4-edge ping-pong, fp8 KV) ----
    fused_attn<<<N, 64, 0, stream>>>(O1, kv8, ea, tmp, bsum, eid2, agg, weab, N);

    // ---- econ GEMM + LN1 fused: hb = LN1(weab@Wec2^T + agg + x + skip) ----
    gemm_fused<0,1,1><<<dim3(1, gy64), 256, 0, stream>>>(
        weab, 64, Wec2, 64, nullptr, hb, 128, N, 64,
        agg, x, O1 + 768, 1024, nullptr, g1, b1l);

    // ---- FFN1: mid = leaky(hb @ W1h^T + b1f) ----
    gemm_fused<1,0,1><<<dim3(2, gy64), 256, 0, stream>>>(
        hb, 128, W1h, 128, b1f, mid, 256, N, 128,
        nullptr, nullptr, nullptr, 0, nullptr, nullptr, nullptr);

    // ---- FFN2 + LN2 fused: out = LN2(hb + mid @ W2h^T + b2f) ----
    gemm_fused<0,2,0><<<dim3(1, gy64), 256, 0, stream>>>(
        mid, 256, W2h, 256, b2f, out, 128, N, 256,
        nullptr, nullptr, nullptr, 0, hb, g2, b2l);
}

// Round 13
// 349.868 us; speedup vs baseline: 1.2038x; 1.2038x over previous
//
#include <hip/hip_runtime.h>
#include <hip/hip_bf16.h>

// ---------------------------------------------------------------------------
// GraphTransformerBlock: TransformerConv(H=2, C=128) + skip + LN + FFN + LN
// R22 = R20 reverted (347.6us verified best). R21's BK=64 two-chunk register
// staging SPILLED to scratch (VGPR_Count 44 < ~48 staged regs + addresses ->
// WRITE_SIZE 216MB = output 100MB + ~116MB scratch; dur 94us). Same root
// cause retro-explains R12 (4-chunk staging, 200MB writes). LESSON: the
// single-chunk-per-barrier-pair structure (R9/R19) is the register-budget
// sweet spot for this template — do not widen K staging in registers.
// Config: all GEMMs BM=64 BK=32 (R18/R19), bijective XCD swizzle (R11),
// x-cast hoisted (R13), fp8-e4m3 KV gather in attn (R20: FETCH 236->138MB,
// attn 75->53us, absmax 0.070 < 0.103).
// O1 row [1024]: q 0-255 | kv-interleaved 256-767 | skip 768-895 | P 896-959
// ---------------------------------------------------------------------------

typedef __attribute__((ext_vector_type(8))) short bf16x8;
typedef __attribute__((ext_vector_type(8))) unsigned short u16x8;
typedef __attribute__((ext_vector_type(4))) float f32x4;
typedef __attribute__((ext_vector_type(2))) float f32x2;

__device__ __forceinline__ float bf2f(unsigned short u) {
    union { float f; unsigned u32; } x; x.u32 = ((unsigned)u) << 16; return x.f;
}
__device__ __forceinline__ unsigned short f2bf(float f) {
    unsigned u = __float_as_uint(f);
    return (unsigned short)((u + 0x7FFFu + ((u >> 16) & 1u)) >> 16);
}

// ---------------- x -> bf16, one shot ---------------------------------------
__global__ __launch_bounds__(256)
void cast_x(const float* __restrict__ x, unsigned short* __restrict__ xh,
            int total8) {
    int t = blockIdx.x * 256 + threadIdx.x;
    if (t >= total8) return;
    const float4 a = *(const float4*)(x + (size_t)t * 8);
    const float4 b = *(const float4*)(x + (size_t)t * 8 + 4);
    u16x8 v;
    v[0] = f2bf(a.x); v[1] = f2bf(a.y); v[2] = f2bf(a.z); v[3] = f2bf(a.w);
    v[4] = f2bf(b.x); v[5] = f2bf(b.y); v[6] = f2bf(b.z); v[7] = f2bf(b.w);
    *(u16x8*)(xh + (size_t)t * 8) = v;
}

// ---------------- O1 KV slice -> fp8 e4m3 packed buffer ---------------------
// kv8[row][512]: byte c = fp8(O1[row][256+c]). 8 values per thread,
// coalesced 16B read / 8B write. total = N*64 groups.
__global__ __launch_bounds__(256)
void cvt_kv(const unsigned short* __restrict__ O1,
            unsigned char* __restrict__ kv8, int total) {
    int t = blockIdx.x * 256 + threadIdx.x;
    if (t >= total) return;
    int row = t >> 6;
    int col = (t & 63) * 8;
    u16x8 v = *(const u16x8*)(O1 + (size_t)row * 1024 + 256 + col);
    int lo = 0, hi = 0;
    lo = __builtin_amdgcn_cvt_pk_fp8_f32(bf2f(v[0]), bf2f(v[1]), lo, false);
    lo = __builtin_amdgcn_cvt_pk_fp8_f32(bf2f(v[2]), bf2f(v[3]), lo, true);
    hi = __builtin_amdgcn_cvt_pk_fp8_f32(bf2f(v[4]), bf2f(v[5]), hi, false);
    hi = __builtin_amdgcn_cvt_pk_fp8_f32(bf2f(v[6]), bf2f(v[7]), hi, true);
    *(int2*)(kv8 + (size_t)row * 512 + col) = make_int2(lo, hi);
}

// ---------------- bf16 MFMA GEMM + optional fused LN epilogue ---------------
// C[M,OC] = act(A[M,K] @ W[OC,K]^T + bias), tile 64 x 128, bf16 A, BK=32.
// EPI=0: plain store. EPI=1 (grid.x==1, OC=128): t = acc+add0+add1+bf16(skip);
// out = LN(t) -> bf16. EPI=2: f = acc+bias; t = bf16(hprev)+f; LN -> f32.
template<int ACT, int EPI, int OUT_BF16>
__global__ __launch_bounds__(256)
void gemm_fused(const unsigned short* __restrict__ Ah, int lda,
                const unsigned short* __restrict__ W, int ldw,
                const float* __restrict__ bias,
                void* __restrict__ outp, int ldo, int M, int K,
                const float* __restrict__ add0, const float* __restrict__ add1,
                const unsigned short* __restrict__ skipp, int skip_ld,
                const unsigned short* __restrict__ hprev,
                const float* __restrict__ lng, const float* __restrict__ lnb) {
    __shared__ unsigned short As[64 * 40];    // pitch 40 elems kills conflicts
    __shared__ unsigned short Bs[128 * 40];
    const int tid = threadIdx.x;
    const int wave = tid >> 6, lane = tid & 63;

    // XCD-chunked bijective block swizzle (m204): verified R11
    // (projection FETCH 100MB -> 14MB).
    int row0, col0;
    {
        const int gx   = gridDim.x;
        const int nwg  = gx * gridDim.y;
        const int orig = blockIdx.y * gx + blockIdx.x;
        const int q8   = nwg >> 3, r8 = nwg & 7;
        const int xcd  = orig & 7, sub = orig >> 3;
        const int swz  = (xcd < r8 ? xcd * (q8 + 1)
                                   : r8 * (q8 + 1) + (xcd - r8) * q8) + sub;
        row0 = (swz / gx) * 64;
        col0 = (swz % gx) * 128;
    }

    const int srow = tid >> 2;                 // 0..63
    const int skg  = (tid & 3) * 8;
    int r0 = row0 + srow;      if (r0 >= M) r0 = 0;
    const int b0 = col0 + srow, b1 = col0 + srow + 64;

    f32x4 acc[8];
    const f32x4 z4 = {0.f, 0.f, 0.f, 0.f};
    #pragma unroll
    for (int j = 0; j < 8; j++) acc[j] = z4;

    const int mrow = wave * 16 + (lane & 15);
    const int kq = (lane >> 4) * 8;
    const int lgrp = lane & 15;

    for (int kt = 0; kt < K; kt += 32) {
        u16x8 a0v = *(const u16x8*)(Ah + (size_t)r0 * lda + kt + skg);
        float4 w0 = *(const float4*)(W + (size_t)b0 * ldw + kt + skg);
        float4 w1 = *(const float4*)(W + (size_t)b1 * ldw + kt + skg);
        __syncthreads();
        *(u16x8*)&As[srow * 40 + skg]         = a0v;
        *(float4*)&Bs[srow * 40 + skg]        = w0;
        *(float4*)&Bs[(srow + 64) * 40 + skg] = w1;
        __syncthreads();
        bf16x8 af0 = *(const bf16x8*)&As[mrow * 40 + kq];
        bf16x8 bfr[8];
        #pragma unroll
        for (int j = 0; j < 8; j++)
            bfr[j] = *(const bf16x8*)&Bs[(j * 16 + lgrp) * 40 + kq];
        #pragma unroll
        for (int j = 0; j < 8; j++)
            acc[j] = __builtin_amdgcn_mfma_f32_16x16x32_bf16(af0, bfr[j], acc[j], 0, 0, 0);
    }

    // C/D layout: col = lane&15, row = (lane>>4)*4 + reg
    if (EPI == 0) {
        const int orow0 = row0 + wave * 16 + ((lane >> 4) << 2);
        const int ocol0 = col0 + lgrp;
        #pragma unroll
        for (int r = 0; r < 4; r++) {
            int row = orow0 + r;
            if (row >= M) continue;
            #pragma unroll
            for (int j = 0; j < 8; j++) {
                int col = ocol0 + j * 16;
                float v = acc[j][r] + (bias ? bias[col] : 0.f);
                if (ACT == 1) v = (v > 0.f) ? v : 0.01f * v;
                if (OUT_BF16) ((unsigned short*)outp)[(size_t)row * ldo + col] = f2bf(v);
                else          ((float*)outp)[(size_t)row * ldo + col] = v;
            }
        }
    } else {
        #pragma unroll
        for (int r = 0; r < 4; r++) {
            int row = row0 + wave * 16 + ((lane >> 4) << 2) + r;
            if (row >= M) continue;
            float t[8];
            #pragma unroll
            for (int j = 0; j < 8; j++) {
                int col = lgrp + j * 16;
                float v = acc[j][r];
                if (EPI == 1) {
                    v += add0[(size_t)row * 128 + col] + add1[(size_t)row * 128 + col]
                       + bf2f(skipp[(size_t)row * skip_ld + col]);
                } else {
                    v += bias[col];
                    v += bf2f(hprev[(size_t)row * 128 + col]);
                }
                t[j] = v;
            }
            float s = 0.f;
            #pragma unroll
            for (int j = 0; j < 8; j++) s += t[j];
            #pragma unroll
            for (int off = 8; off >= 1; off >>= 1) s += __shfl_xor(s, off);
            float mu = s * (1.f / 128.f);
            float q = 0.f;
            #pragma unroll
            for (int j = 0; j < 8; j++) { float d = t[j] - mu; q += d * d; }
            #pragma unroll
            for (int off = 8; off >= 1; off >>= 1) q += __shfl_xor(q, off);
            float rs = rsqrtf(q * (1.f / 128.f) + 1e-5f);
            #pragma unroll
            for (int j = 0; j < 8; j++) {
                int col = lgrp + j * 16;
                float o = (t[j] - mu) * rs * lng[col] + lnb[col];
                if (EPI == 1) ((unsigned short*)outp)[(size_t)row * ldo + col] = f2bf(o);
                else          ((float*)outp)[(size_t)row * ldo + col] = o;
            }
        }
    }
}

// ---------------- prep: weights + deg_count, one dispatch -------------------
#define WPREP 205824
__global__ void prep_all(const float* __restrict__ Wq, const float* __restrict__ bq,
                         const float* __restrict__ Wk, const float* __restrict__ bk,
                         const float* __restrict__ Wv, const float* __restrict__ bv,
                         const float* __restrict__ We, const float* __restrict__ Wsk,
                         const float* __restrict__ bsk,
                         const float* __restrict__ W1, const float* __restrict__ W2,
                         unsigned short* __restrict__ Wcat, float* __restrict__ bcat,
                         unsigned short* __restrict__ W1h, unsigned short* __restrict__ W2h,
                         unsigned short* __restrict__ Wec2,
                         const int* __restrict__ dst, int* __restrict__ deg, int E) {
    int k = blockIdx.x * 256 + threadIdx.x;
    if (k >= WPREP) {                       // deg count segment
        int e = k - WPREP;
        if (e < E) atomicAdd(&deg[dst[e]], 1);
        return;
    }
    if (k < 131072) {                       // Wcat [1024][128]
        int oc = k >> 7, r = k & 127;
        float v;
        if (oc < 256) v = Wq[(size_t)oc * 128 + r];
        else if (oc < 768) {
            int rr = oc - 256, g = rr >> 3, p = rr & 7;
            int h = g >> 5, ch = h * 128 + (g & 31) * 4 + (p & 3);
            v = (p < 4) ? Wk[(size_t)ch * 128 + r] : Wv[(size_t)ch * 128 + r];
        } else if (oc < 896) v = Wsk[(size_t)(oc - 768) * 128 + r];
        else if (oc < 960) {
            int qd = oc - 896, h = qd >> 5, t = qd & 31;
            float s = 0.f;
            for (int c = 0; c < 128; c++)
                s += Wq[(size_t)(h*128 + c) * 128 + r] * We[(size_t)(h*128 + c) * 32 + t];
            v = s;
        } else v = 0.f;
        Wcat[k] = f2bf(v);
    } else if (k < 132096) {                // bcat [1024]
        int oc = k - 131072;
        float v;
        if (oc < 256) v = bq[oc];
        else if (oc < 768) {
            int rr = oc - 256, g = rr >> 3, p = rr & 7;
            int ch = (g >> 5) * 128 + (g & 31) * 4 + (p & 3);
            v = (p < 4) ? bk[ch] : bv[ch];
        } else if (oc < 896) v = bsk[oc - 768];
        else if (oc < 960) {
            int qd = oc - 896, h = qd >> 5, t = qd & 31;
            float s = 0.f;
            for (int c = 0; c < 128; c++)
                s += bq[h*128 + c] * We[(size_t)(h*128 + c) * 32 + t];
            v = s;
        } else v = 0.f;
        bcat[oc] = v;
    } else if (k < 164864) {                // W1h
        int j = k - 132096;
        W1h[j] = f2bf(W1[j]);
    } else if (k < 197632) {                // W2h
        int j = k - 164864;
        W2h[j] = f2bf(W2[j]);
    } else {                                // Wec2 [128][64], 0.5 head-mean folded
        int j = k - 197632;
        int c = j >> 6, tt = j & 63, h = tt >> 5, t = tt & 31;
        Wec2[j] = f2bf(0.5f * We[(size_t)(h * 128 + c) * 32 + t]);
    }
}

// ---------------- CSR scan --------------------------------------------------
__global__ __launch_bounds__(256)
void scan_block(const int* __restrict__ deg, int* __restrict__ tmp,
                int* __restrict__ bsum, int n) {
    __shared__ int lds[256];
    int i = blockIdx.x * 256 + threadIdx.x;
    int v = (i < n) ? deg[i] : 0;
    lds[threadIdx.x] = v;
    __syncthreads();
    #pragma unroll
    for (int off = 1; off < 256; off <<= 1) {
        int t = (threadIdx.x >= off) ? lds[threadIdx.x - off] : 0;
        __syncthreads();
        lds[threadIdx.x] += t;
        __syncthreads();
    }
    if (i < n) tmp[i] = lds[threadIdx.x];
    if (threadIdx.x == 255) bsum[blockIdx.x] = lds[255];
}
__global__ __launch_bounds__(1024)
void scan_bsum(int* __restrict__ bsum, int nb) {
    __shared__ int lds[1024];
    int v = (threadIdx.x < nb) ? bsum[threadIdx.x] : 0;
    lds[threadIdx.x] = v;
    __syncthreads();
    #pragma unroll
    for (int off = 1; off < 1024; off <<= 1) {
        int t = (threadIdx.x >= off) ? lds[threadIdx.x - off] : 0;
        __syncthreads();
        lds[threadIdx.x] += t;
        __syncthreads();
    }
    if (threadIdx.x < nb) bsum[threadIdx.x] = lds[threadIdx.x] - v;  // exclusive
}
// row_start(d) = (d==0) ? 0 : tmp[d-1] + sbx[(d-1)>>8]
__global__ void csr_fill(const int* __restrict__ src, const int* __restrict__ dst,
                         const int* __restrict__ tmp, const int* __restrict__ sbx,
                         int* __restrict__ cnt, int2* __restrict__ eid2, int E) {
    int e = blockIdx.x * blockDim.x + threadIdx.x;
    if (e < E) {
        int d = dst[e];
        int start = (d == 0) ? 0 : (tmp[d - 1] + sbx[(d - 1) >> 8]);
        int pos = start + atomicAdd(&cnt[d], 1);
        eid2[pos] = make_int2(e, src[e]);
    }
}

// ---------------- fused attention: 1 wave/block, 4-edge ping-pong, fp8 KV ---
// Pipeline invariant at loop top: kvX holds data for group at j; idx holds
// indices for group at j+4. Every exp() slot guarded by (jb+i<jend); OOB
// slots load nothing (sentinel zeros, fp8 0x00 == 0.0f) and contribute w=0.
// Epilogue: per-head normalize, head-mean via shfl_xor(32) -> agg[N,128].

#define ATTN_LOADG(kv, ea, idx)                                               \
    _Pragma("unroll")                                                         \
    for (int i = 0; i < 4; i++) {                                             \
        if (idx[i].y >= 0) {                                                  \
            kv[i] = *(const uint2*)(KV8 + (size_t)idx[i].y * 512 + lane * 8); \
            ea[i] = EA[(size_t)idx[i].x * 32 + hl];                           \
        } else { kv[i] = zkv; ea[i] = 0.f; }                                  \
    }

#define ATTN_FETCHIDX(idx, base)                                              \
    _Pragma("unroll")                                                         \
    for (int i = 0; i < 4; i++)                                               \
        idx[i] = (base + i < jend) ? eid2[base + i] : make_int2(0, -1);

#define ATTN_COMPUTE(kv, ea, jb)                                              \
    {                                                                         \
        float d_[4];                                                          \
        f32x2 vlo_[4], vhi_[4];                                               \
        _Pragma("unroll")                                                     \
        for (int i = 0; i < 4; i++) {                                         \
            f32x2 k01 = __builtin_amdgcn_cvt_pk_f32_fp8((int)kv[i].x, false); \
            f32x2 k23 = __builtin_amdgcn_cvt_pk_f32_fp8((int)kv[i].x, true);  \
            vlo_[i]   = __builtin_amdgcn_cvt_pk_f32_fp8((int)kv[i].y, false); \
            vhi_[i]   = __builtin_amdgcn_cvt_pk_f32_fp8((int)kv[i].y, true);  \
            d_[i] = qv.x*k01.x + qv.y*k01.y + qv.z*k23.x + qv.w*k23.y         \
                  + pd*ea[i];                                                 \
        }                                                                     \
        _Pragma("unroll")                                                     \
        for (int off = 16; off >= 1; off >>= 1) {                             \
            _Pragma("unroll")                                                 \
            for (int i = 0; i < 4; i++) d_[i] += __shfl_xor(d_[i], off);      \
        }                                                                     \
        _Pragma("unroll")                                                     \
        for (int i = 0; i < 4; i++) {                                         \
            float wv = ((jb) + i < jend) ? __expf(d_[i] * inv) : 0.f;         \
            l += wv;                                                          \
            acc.x += wv * vlo_[i].x;                                          \
            acc.y += wv * vlo_[i].y;                                          \
            acc.z += wv * vhi_[i].x;                                          \
            acc.w += wv * vhi_[i].y;                                          \
            wacc  += wv * ea[i];                                              \
        }                                                                     \
    }

__global__ __launch_bounds__(64)
void fused_attn(const unsigned short* __restrict__ O1,
                const unsigned char* __restrict__ KV8,
                const float* __restrict__ EA,
                const int* __restrict__ tmp, const int* __restrict__ sbx,
                const int2* __restrict__ eid2,
                float* __restrict__ agg, unsigned short* __restrict__ weab, int N) {
    const int node = blockIdx.x;
    const int lane = threadIdx.x;
    const int hl = lane & 31;
    const int choff = (lane >> 5) * 128 + (hl << 2);
    const float inv = 0.08838834764831845f;  // 1/sqrt(128)

    ushort4 q4 = *(const ushort4*)(O1 + (size_t)node * 1024 + choff);
    float4 qv = make_float4(bf2f(q4.x), bf2f(q4.y), bf2f(q4.z), bf2f(q4.w));
    float pd = bf2f(O1[(size_t)node * 1024 + 896 + lane]);

    const int j0 = (node == 0) ? 0 : (tmp[node - 1] + sbx[(node - 1) >> 8]);
    const int jend = tmp[node] + sbx[node >> 8];

    float l = 0.f, wacc = 0.f;
    float4 acc = make_float4(0.f, 0.f, 0.f, 0.f);

    const uint2 zkv = make_uint2(0u, 0u);
    uint2 kvA[4], kvB[4];
    float eaA[4], eaB[4];
    int2 idx[4];

    int j = j0;
    if (j < jend) {
        // group 0 data -> A (inline indices)
        #pragma unroll
        for (int i = 0; i < 4; i++) {
            if (j + i < jend) {
                int2 es = eid2[j + i];
                kvA[i] = *(const uint2*)(KV8 + (size_t)es.y * 512 + lane * 8);
                eaA[i] = EA[(size_t)es.x * 32 + hl];
            } else { kvA[i] = zkv; eaA[i] = 0.f; }
        }
        // indices for group 1
        ATTN_FETCHIDX(idx, j + 4);

        while (j < jend) {
            // phase A: data j+4 -> B, indices j+8, compute A(j)
            ATTN_LOADG(kvB, eaB, idx);
            ATTN_FETCHIDX(idx, j + 8);
            ATTN_COMPUTE(kvA, eaA, j);
            j += 4;
            if (j >= jend) break;

            // phase B: data j+4 -> A, indices j+8, compute B(j)
            ATTN_LOADG(kvA, eaA, idx);
            ATTN_FETCHIDX(idx, j + 8);
            ATTN_COMPUTE(kvB, eaB, j);
            j += 4;
        }
    }

    float r = 1.f / (l + 1e-16f);
    weab[(size_t)node * 64 + lane] = f2bf(wacc * r);
    float ax = acc.x * r, ay = acc.y * r, az = acc.z * r, aw = acc.w * r;
    float mx = 0.5f * (ax + __shfl_xor(ax, 32));
    float my = 0.5f * (ay + __shfl_xor(ay, 32));
    float mz = 0.5f * (az + __shfl_xor(az, 32));
    float mw = 0.5f * (aw + __shfl_xor(aw, 32));
    if (lane < 32)
        *(float4*)(agg + (size_t)node * 128 + hl * 4) = make_float4(mx, my, mz, mw);
}

// ---------------------------------------------------------------------------
extern "C" void kernel_launch(void* const* d_in, const int* in_sizes, int n_in,
                              void* d_out, int out_size, void* d_ws, size_t ws_size,
                              hipStream_t stream) {
    const float* x    = (const float*)d_in[0];
    const int*   ei   = (const int*)d_in[1];
    const float* ea   = (const float*)d_in[2];
    const float* Wq   = (const float*)d_in[3];
    const float* bq   = (const float*)d_in[4];
    const float* Wk   = (const float*)d_in[5];
    const float* bk   = (const float*)d_in[6];
    const float* Wv   = (const float*)d_in[7];
    const float* bv   = (const float*)d_in[8];
    const float* We   = (const float*)d_in[9];
    const float* Wsk  = (const float*)d_in[10];
    const float* bsk  = (const float*)d_in[11];
    const float* g1   = (const float*)d_in[12];
    const float* b1l  = (const float*)d_in[13];
    const float* W1   = (const float*)d_in[14];
    const float* b1f  = (const float*)d_in[15];
    const float* W2   = (const float*)d_in[16];
    const float* b2f  = (const float*)d_in[17];
    const float* g2   = (const float*)d_in[18];
    const float* b2l  = (const float*)d_in[19];
    float* out = (float*)d_out;

    const int N = in_sizes[0] / 128;
    const int E = in_sizes[2] / 32;
    const int* src = ei;
    const int* dst = ei + E;

    char* w = (char*)d_ws;
    unsigned short* O1   = (unsigned short*)w;  w += (size_t)N * 2048;  // [N,1024] bf16
    float* agg           = (float*)w;           w += (size_t)N * 512;   // [N,128] f32
    unsigned short* weab = (unsigned short*)w;  w += (size_t)N * 128;   // [N,64] bf16
    unsigned short* hb   = (unsigned short*)w;  w += (size_t)N * 256;   // [N,128] bf16
    unsigned char* kv8   = (unsigned char*)w;   w += (size_t)N * 512;   // [N,512] fp8
    unsigned short* Wcat = (unsigned short*)w;  w += 1024 * 128 * 2;
    float* bcat          = (float*)w;           w += 1024 * 4;
    unsigned short* W1h  = (unsigned short*)w;  w += 256 * 128 * 2;
    unsigned short* W2h  = (unsigned short*)w;  w += 128 * 256 * 2;
    unsigned short* Wec2 = (unsigned short*)w;  w += 128 * 64 * 2;
    int2* eid2           = (int2*)w;            w += (size_t)E * 8;
    int* deg  = (int*)w;            // [N] — zeroed by memset (with cnt)
    int* cnt  = deg + N;            // [N]
    int* tmp  = cnt + N;            // [N]
    int* bsum = tmp + N;            // <=1024

    // aliases of agg (timeline-disjoint):
    //   xh  bf16 [N,128] (N*256 B) — written by cast_x, read by projection;
    //                                 dead once fused_attn writes agg.
    //   mid bf16 [N,256] (N*512 B) — written by FFN1 after econ consumed agg.
    unsigned short* xh  = (unsigned short*)agg;
    unsigned short* mid = (unsigned short*)agg;

    const int gy64  = (N + 63) / 64;
    const int nb = (N + 255) / 256;

    // ---- zero deg+cnt (memset node), x->bf16, prep weights + deg_count ----
    hipMemsetAsync(deg, 0, (size_t)2 * N * 4, stream);
    const int total8 = (N * 128) / 8;
    cast_x<<<(total8 + 255) / 256, 256, 0, stream>>>(x, xh, total8);
    prep_all<<<(WPREP + E + 255) / 256, 256, 0, stream>>>(
        Wq, bq, Wk, bk, Wv, bv, We, Wsk, bsk, W1, W2,
        Wcat, bcat, W1h, W2h, Wec2, dst, deg, E);

    // ---- projection GEMM (bf16 A, BM=64): O1 = xh @ Wcat^T + bcat ----
    gemm_fused<0,0,1><<<dim3(8, gy64), 256, 0, stream>>>(
        xh, 128, Wcat, 128, bcat, O1, 1024, N, 128,
        nullptr, nullptr, nullptr, 0, nullptr, nullptr, nullptr);

    // ---- KV slice -> fp8 packed buffer ----
    const int totkv = N * 64;
    cvt_kv<<<(totkv + 255) / 256, 256, 0, stream>>>(O1, kv8, totkv);

    // ---- CSR: scan + fill ----
    scan_block<<<nb, 256, 0, stream>>>(deg, tmp, bsum, N);
    scan_bsum<<<1, 1024, 0, stream>>>(bsum, nb);
    csr_fill<<<(E + 255)/256, 256, 0, stream>>>(src, dst, tmp, bsum, cnt, eid2, E);

    // ---- attention (1 wave/block, 4-edge ping-pong, fp8 KV) ----
    fused_attn<<<N, 64, 0, stream>>>(O1, kv8, ea, tmp, bsum, eid2, agg, weab, N);

    // ---- econ GEMM + LN1 fused: hb = LN1(weab@Wec2^T + agg + x + skip) ----
    gemm_fused<0,1,1><<<dim3(1, gy64), 256, 0, stream>>>(
        weab, 64, Wec2, 64, nullptr, hb, 128, N, 64,
        agg, x, O1 + 768, 1024, nullptr, g1, b1l);

    // ---- FFN1: mid = leaky(hb @ W1h^T + b1f) ----
    gemm_fused<1,0,1><<<dim3(2, gy64), 256, 0, stream>>>(
        hb, 128, W1h, 128, b1f, mid, 256, N, 128,
        nullptr, nullptr, nullptr, 0, nullptr, nullptr, nullptr);

    // ---- FFN2 + LN2 fused: out = LN2(hb + mid @ W2h^T + b2f) ----
    gemm_fused<0,2,0><<<dim3(1, gy64), 256, 0, stream>>>(
        mid, 256, W2h, 256, b2f, out, 128, N, 256,
        nullptr, nullptr, nullptr, 0, hb, g2, b2l);
}

// Round 14
// 338.412 us; speedup vs baseline: 1.2446x; 1.0339x over previous
//
#include <hip/hip_runtime.h>
#include <hip/hip_bf16.h>

// ---------------------------------------------------------------------------
// GraphTransformerBlock: TransformerConv(H=2, C=128) + skip + LN + FFN + LN
// R23: R22 base (349.9us; GEMM body frozen — R12/R17/R21 all showed the
// single-chunk BM=64 BK=32 structure is the sweet spot) + dispatch-count
// reduction (12 -> 9):
//   - cast_x folded into prep_all (new tail segment of the segmented grid).
//   - scan_bsum (1-block kernel, whole-GPU bubble) DELETED: each fill block
//     re-derives the <=1024-entry bsum exclusive scan in LDS (L2-resident,
//     ~196 ints); block 0 publishes sbxg for fused_attn. bsum now read-only.
//   - cvt_kv merged into the fill dispatch (role split by blockIdx; both
//     depend only on projection+scan_block).
// Config: all GEMMs BM=64 BK=32 (R18/R19), bijective XCD swizzle (R11),
// fp8-e4m3 KV gather in attn (R20: attn 75->53us, absmax 0.070 < 0.103).
// O1 row [1024]: q 0-255 | kv-interleaved 256-767 | skip 768-895 | P 896-959
// ---------------------------------------------------------------------------

typedef __attribute__((ext_vector_type(8))) short bf16x8;
typedef __attribute__((ext_vector_type(8))) unsigned short u16x8;
typedef __attribute__((ext_vector_type(4))) float f32x4;
typedef __attribute__((ext_vector_type(2))) float f32x2;

__device__ __forceinline__ float bf2f(unsigned short u) {
    union { float f; unsigned u32; } x; x.u32 = ((unsigned)u) << 16; return x.f;
}
__device__ __forceinline__ unsigned short f2bf(float f) {
    unsigned u = __float_as_uint(f);
    return (unsigned short)((u + 0x7FFFu + ((u >> 16) & 1u)) >> 16);
}

// ---------------- bf16 MFMA GEMM + optional fused LN epilogue ---------------
// C[M,OC] = act(A[M,K] @ W[OC,K]^T + bias), tile 64 x 128, bf16 A, BK=32.
// EPI=0: plain store. EPI=1 (grid.x==1, OC=128): t = acc+add0+add1+bf16(skip);
// out = LN(t) -> bf16. EPI=2: f = acc+bias; t = bf16(hprev)+f; LN -> f32.
template<int ACT, int EPI, int OUT_BF16>
__global__ __launch_bounds__(256)
void gemm_fused(const unsigned short* __restrict__ Ah, int lda,
                const unsigned short* __restrict__ W, int ldw,
                const float* __restrict__ bias,
                void* __restrict__ outp, int ldo, int M, int K,
                const float* __restrict__ add0, const float* __restrict__ add1,
                const unsigned short* __restrict__ skipp, int skip_ld,
                const unsigned short* __restrict__ hprev,
                const float* __restrict__ lng, const float* __restrict__ lnb) {
    __shared__ unsigned short As[64 * 40];    // pitch 40 elems kills conflicts
    __shared__ unsigned short Bs[128 * 40];
    const int tid = threadIdx.x;
    const int wave = tid >> 6, lane = tid & 63;

    // XCD-chunked bijective block swizzle (m204): verified R11
    // (projection FETCH 100MB -> 14MB; R22: 7.4MB).
    int row0, col0;
    {
        const int gx   = gridDim.x;
        const int nwg  = gx * gridDim.y;
        const int orig = blockIdx.y * gx + blockIdx.x;
        const int q8   = nwg >> 3, r8 = nwg & 7;
        const int xcd  = orig & 7, sub = orig >> 3;
        const int swz  = (xcd < r8 ? xcd * (q8 + 1)
                                   : r8 * (q8 + 1) + (xcd - r8) * q8) + sub;
        row0 = (swz / gx) * 64;
        col0 = (swz % gx) * 128;
    }

    const int srow = tid >> 2;                 // 0..63
    const int skg  = (tid & 3) * 8;
    int r0 = row0 + srow;      if (r0 >= M) r0 = 0;
    const int b0 = col0 + srow, b1 = col0 + srow + 64;

    f32x4 acc[8];
    const f32x4 z4 = {0.f, 0.f, 0.f, 0.f};
    #pragma unroll
    for (int j = 0; j < 8; j++) acc[j] = z4;

    const int mrow = wave * 16 + (lane & 15);
    const int kq = (lane >> 4) * 8;
    const int lgrp = lane & 15;

    for (int kt = 0; kt < K; kt += 32) {
        u16x8 a0v = *(const u16x8*)(Ah + (size_t)r0 * lda + kt + skg);
        float4 w0 = *(const float4*)(W + (size_t)b0 * ldw + kt + skg);
        float4 w1 = *(const float4*)(W + (size_t)b1 * ldw + kt + skg);
        __syncthreads();
        *(u16x8*)&As[srow * 40 + skg]         = a0v;
        *(float4*)&Bs[srow * 40 + skg]        = w0;
        *(float4*)&Bs[(srow + 64) * 40 + skg] = w1;
        __syncthreads();
        bf16x8 af0 = *(const bf16x8*)&As[mrow * 40 + kq];
        bf16x8 bfr[8];
        #pragma unroll
        for (int j = 0; j < 8; j++)
            bfr[j] = *(const bf16x8*)&Bs[(j * 16 + lgrp) * 40 + kq];
        #pragma unroll
        for (int j = 0; j < 8; j++)
            acc[j] = __builtin_amdgcn_mfma_f32_16x16x32_bf16(af0, bfr[j], acc[j], 0, 0, 0);
    }

    // C/D layout: col = lane&15, row = (lane>>4)*4 + reg
    if (EPI == 0) {
        const int orow0 = row0 + wave * 16 + ((lane >> 4) << 2);
        const int ocol0 = col0 + lgrp;
        #pragma unroll
        for (int r = 0; r < 4; r++) {
            int row = orow0 + r;
            if (row >= M) continue;
            #pragma unroll
            for (int j = 0; j < 8; j++) {
                int col = ocol0 + j * 16;
                float v = acc[j][r] + (bias ? bias[col] : 0.f);
                if (ACT == 1) v = (v > 0.f) ? v : 0.01f * v;
                if (OUT_BF16) ((unsigned short*)outp)[(size_t)row * ldo + col] = f2bf(v);
                else          ((float*)outp)[(size_t)row * ldo + col] = v;
            }
        }
    } else {
        #pragma unroll
        for (int r = 0; r < 4; r++) {
            int row = row0 + wave * 16 + ((lane >> 4) << 2) + r;
            if (row >= M) continue;
            float t[8];
            #pragma unroll
            for (int j = 0; j < 8; j++) {
                int col = lgrp + j * 16;
                float v = acc[j][r];
                if (EPI == 1) {
                    v += add0[(size_t)row * 128 + col] + add1[(size_t)row * 128 + col]
                       + bf2f(skipp[(size_t)row * skip_ld + col]);
                } else {
                    v += bias[col];
                    v += bf2f(hprev[(size_t)row * 128 + col]);
                }
                t[j] = v;
            }
            float s = 0.f;
            #pragma unroll
            for (int j = 0; j < 8; j++) s += t[j];
            #pragma unroll
            for (int off = 8; off >= 1; off >>= 1) s += __shfl_xor(s, off);
            float mu = s * (1.f / 128.f);
            float q = 0.f;
            #pragma unroll
            for (int j = 0; j < 8; j++) { float d = t[j] - mu; q += d * d; }
            #pragma unroll
            for (int off = 8; off >= 1; off >>= 1) q += __shfl_xor(q, off);
            float rs = rsqrtf(q * (1.f / 128.f) + 1e-5f);
            #pragma unroll
            for (int j = 0; j < 8; j++) {
                int col = lgrp + j * 16;
                float o = (t[j] - mu) * rs * lng[col] + lnb[col];
                if (EPI == 1) ((unsigned short*)outp)[(size_t)row * ldo + col] = f2bf(o);
                else          ((float*)outp)[(size_t)row * ldo + col] = o;
            }
        }
    }
}

// ---------------- prep: weights + deg_count + x-cast, one dispatch ----------
#define WPREP 205824
__global__ void prep_all(const float* __restrict__ Wq, const float* __restrict__ bq,
                         const float* __restrict__ Wk, const float* __restrict__ bk,
                         const float* __restrict__ Wv, const float* __restrict__ bv,
                         const float* __restrict__ We, const float* __restrict__ Wsk,
                         const float* __restrict__ bsk,
                         const float* __restrict__ W1, const float* __restrict__ W2,
                         unsigned short* __restrict__ Wcat, float* __restrict__ bcat,
                         unsigned short* __restrict__ W1h, unsigned short* __restrict__ W2h,
                         unsigned short* __restrict__ Wec2,
                         const int* __restrict__ dst, int* __restrict__ deg, int E,
                         const float* __restrict__ x, unsigned short* __restrict__ xh,
                         int total8) {
    int k = blockIdx.x * 256 + threadIdx.x;
    if (k >= WPREP) {
        int e = k - WPREP;
        if (e < E) { atomicAdd(&deg[dst[e]], 1); return; }  // deg count segment
        int t = e - E;                                       // x -> bf16 segment
        if (t < total8) {
            const float4 a = *(const float4*)(x + (size_t)t * 8);
            const float4 b = *(const float4*)(x + (size_t)t * 8 + 4);
            u16x8 v;
            v[0] = f2bf(a.x); v[1] = f2bf(a.y); v[2] = f2bf(a.z); v[3] = f2bf(a.w);
            v[4] = f2bf(b.x); v[5] = f2bf(b.y); v[6] = f2bf(b.z); v[7] = f2bf(b.w);
            *(u16x8*)(xh + (size_t)t * 8) = v;
        }
        return;
    }
    if (k < 131072) {                       // Wcat [1024][128]
        int oc = k >> 7, r = k & 127;
        float v;
        if (oc < 256) v = Wq[(size_t)oc * 128 + r];
        else if (oc < 768) {
            int rr = oc - 256, g = rr >> 3, p = rr & 7;
            int h = g >> 5, ch = h * 128 + (g & 31) * 4 + (p & 3);
            v = (p < 4) ? Wk[(size_t)ch * 128 + r] : Wv[(size_t)ch * 128 + r];
        } else if (oc < 896) v = Wsk[(size_t)(oc - 768) * 128 + r];
        else if (oc < 960) {
            int qd = oc - 896, h = qd >> 5, t = qd & 31;
            float s = 0.f;
            for (int c = 0; c < 128; c++)
                s += Wq[(size_t)(h*128 + c) * 128 + r] * We[(size_t)(h*128 + c) * 32 + t];
            v = s;
        } else v = 0.f;
        Wcat[k] = f2bf(v);
    } else if (k < 132096) {                // bcat [1024]
        int oc = k - 131072;
        float v;
        if (oc < 256) v = bq[oc];
        else if (oc < 768) {
            int rr = oc - 256, g = rr >> 3, p = rr & 7;
            int ch = (g >> 5) * 128 + (g & 31) * 4 + (p & 3);
            v = (p < 4) ? bk[ch] : bv[ch];
        } else if (oc < 896) v = bsk[oc - 768];
        else if (oc < 960) {
            int qd = oc - 896, h = qd >> 5, t = qd & 31;
            float s = 0.f;
            for (int c = 0; c < 128; c++)
                s += bq[h*128 + c] * We[(size_t)(h*128 + c) * 32 + t];
            v = s;
        } else v = 0.f;
        bcat[oc] = v;
    } else if (k < 164864) {                // W1h
        int j = k - 132096;
        W1h[j] = f2bf(W1[j]);
    } else if (k < 197632) {                // W2h
        int j = k - 164864;
        W2h[j] = f2bf(W2[j]);
    } else {                                // Wec2 [128][64], 0.5 head-mean folded
        int j = k - 197632;
        int c = j >> 6, tt = j & 63, h = tt >> 5, t = tt & 31;
        Wec2[j] = f2bf(0.5f * We[(size_t)(h * 128 + c) * 32 + t]);
    }
}

// ---------------- CSR block scan --------------------------------------------
__global__ __launch_bounds__(256)
void scan_block(const int* __restrict__ deg, int* __restrict__ tmp,
                int* __restrict__ bsum, int n) {
    __shared__ int lds[256];
    int i = blockIdx.x * 256 + threadIdx.x;
    int v = (i < n) ? deg[i] : 0;
    lds[threadIdx.x] = v;
    __syncthreads();
    #pragma unroll
    for (int off = 1; off < 256; off <<= 1) {
        int t = (threadIdx.x >= off) ? lds[threadIdx.x - off] : 0;
        __syncthreads();
        lds[threadIdx.x] += t;
        __syncthreads();
    }
    if (i < n) tmp[i] = lds[threadIdx.x];
    if (threadIdx.x == 255) bsum[blockIdx.x] = lds[255];
}

// ---------------- fill + cvt_kv merged dispatch ------------------------------
// Blocks [0, nbf): csr_fill — each block re-derives the exclusive scan of
// bsum (read-only, nb <= 1024, chunked with carry) in LDS, then scatters
// edges. Block 0 also publishes sbxg for fused_attn.
// Blocks [nbf, nbf+nbc): cvt_kv — O1 KV slice -> fp8 e4m3 packed kv8.
// row_start(d) = (d==0) ? 0 : tmp[d-1] + sbx[(d-1)>>8]
__global__ __launch_bounds__(256)
void fill_cvt(const int* __restrict__ src, const int* __restrict__ dst,
              const int* __restrict__ tmp, const int* __restrict__ bsum, int nb,
              int* __restrict__ sbxg, int* __restrict__ cnt,
              int2* __restrict__ eid2, int E,
              const unsigned short* __restrict__ O1,
              unsigned char* __restrict__ kv8, int totkv, int nbf) {
    const int tid = threadIdx.x;
    if ((int)blockIdx.x >= nbf) {
        // ---- cvt_kv role ----
        int t = ((int)blockIdx.x - nbf) * 256 + tid;
        if (t >= totkv) return;
        int row = t >> 6;
        int col = (t & 63) * 8;
        u16x8 v = *(const u16x8*)(O1 + (size_t)row * 1024 + 256 + col);
        int lo = 0, hi = 0;
        lo = __builtin_amdgcn_cvt_pk_fp8_f32(bf2f(v[0]), bf2f(v[1]), lo, false);
        lo = __builtin_amdgcn_cvt_pk_fp8_f32(bf2f(v[2]), bf2f(v[3]), lo, true);
        hi = __builtin_amdgcn_cvt_pk_fp8_f32(bf2f(v[4]), bf2f(v[5]), hi, false);
        hi = __builtin_amdgcn_cvt_pk_fp8_f32(bf2f(v[6]), bf2f(v[7]), hi, true);
        *(int2*)(kv8 + (size_t)row * 512 + col) = make_int2(lo, hi);
        return;
    }
    // ---- fill role: local exclusive scan of bsum into sbx ----
    __shared__ int lds[256];
    __shared__ int sbx[1024];
    int carry = 0;
    for (int base = 0; base < nb; base += 256) {
        int v = (base + tid < nb) ? bsum[base + tid] : 0;
        __syncthreads();                       // protect prior-iter lds reads
        lds[tid] = v;
        __syncthreads();
        #pragma unroll
        for (int off = 1; off < 256; off <<= 1) {
            int t2 = (tid >= off) ? lds[tid - off] : 0;
            __syncthreads();
            lds[tid] += t2;
            __syncthreads();
        }
        if (base + tid < nb) sbx[base + tid] = carry + lds[tid] - v;  // exclusive
        carry += lds[255];
    }
    __syncthreads();                           // sbx visible block-wide
    if (blockIdx.x == 0)
        for (int i = tid; i < nb; i += 256) sbxg[i] = sbx[i];
    int e = (int)blockIdx.x * 256 + tid;
    if (e < E) {
        int d = dst[e];
        int start = (d == 0) ? 0 : (tmp[d - 1] + sbx[(d - 1) >> 8]);
        int pos = start + atomicAdd(&cnt[d], 1);
        eid2[pos] = make_int2(e, src[e]);
    }
}

// ---------------- fused attention: 1 wave/block, 4-edge ping-pong, fp8 KV ---
// Pipeline invariant at loop top: kvX holds data for group at j; idx holds
// indices for group at j+4. Every exp() slot guarded by (jb+i<jend); OOB
// slots load nothing (sentinel zeros, fp8 0x00 == 0.0f) and contribute w=0.
// Epilogue: per-head normalize, head-mean via shfl_xor(32) -> agg[N,128].

#define ATTN_LOADG(kv, ea, idx)                                               \
    _Pragma("unroll")                                                         \
    for (int i = 0; i < 4; i++) {                                             \
        if (idx[i].y >= 0) {                                                  \
            kv[i] = *(const uint2*)(KV8 + (size_t)idx[i].y * 512 + lane * 8); \
            ea[i] = EA[(size_t)idx[i].x * 32 + hl];                           \
        } else { kv[i] = zkv; ea[i] = 0.f; }                                  \
    }

#define ATTN_FETCHIDX(idx, base)                                              \
    _Pragma("unroll")                                                         \
    for (int i = 0; i < 4; i++)                                               \
        idx[i] = (base + i < jend) ? eid2[base + i] : make_int2(0, -1);

#define ATTN_COMPUTE(kv, ea, jb)                                              \
    {                                                                         \
        float d_[4];                                                          \
        f32x2 vlo_[4], vhi_[4];                                               \
        _Pragma("unroll")                                                     \
        for (int i = 0; i < 4; i++) {                                         \
            f32x2 k01 = __builtin_amdgcn_cvt_pk_f32_fp8((int)kv[i].x, false); \
            f32x2 k23 = __builtin_amdgcn_cvt_pk_f32_fp8((int)kv[i].x, true);  \
            vlo_[i]   = __builtin_amdgcn_cvt_pk_f32_fp8((int)kv[i].y, false); \
            vhi_[i]   = __builtin_amdgcn_cvt_pk_f32_fp8((int)kv[i].y, true);  \
            d_[i] = qv.x*k01.x + qv.y*k01.y + qv.z*k23.x + qv.w*k23.y         \
                  + pd*ea[i];                                                 \
        }                                                                     \
        _Pragma("unroll")                                                     \
        for (int off = 16; off >= 1; off >>= 1) {                             \
            _Pragma("unroll")                                                 \
            for (int i = 0; i < 4; i++) d_[i] += __shfl_xor(d_[i], off);      \
        }                                                                     \
        _Pragma("unroll")                                                     \
        for (int i = 0; i < 4; i++) {                                         \
            float wv = ((jb) + i < jend) ? __expf(d_[i] * inv) : 0.f;         \
            l += wv;                                                          \
            acc.x += wv * vlo_[i].x;                                          \
            acc.y += wv * vlo_[i].y;                                          \
            acc.z += wv * vhi_[i].x;                                          \
            acc.w += wv * vhi_[i].y;                                          \
            wacc  += wv * ea[i];                                              \
        }                                                                     \
    }

__global__ __launch_bounds__(64)
void fused_attn(const unsigned short* __restrict__ O1,
                const unsigned char* __restrict__ KV8,
                const float* __restrict__ EA,
                const int* __restrict__ tmp, const int* __restrict__ sbx,
                const int2* __restrict__ eid2,
                float* __restrict__ agg, unsigned short* __restrict__ weab, int N) {
    const int node = blockIdx.x;
    const int lane = threadIdx.x;
    const int hl = lane & 31;
    const int choff = (lane >> 5) * 128 + (hl << 2);
    const float inv = 0.08838834764831845f;  // 1/sqrt(128)

    ushort4 q4 = *(const ushort4*)(O1 + (size_t)node * 1024 + choff);
    float4 qv = make_float4(bf2f(q4.x), bf2f(q4.y), bf2f(q4.z), bf2f(q4.w));
    float pd = bf2f(O1[(size_t)node * 1024 + 896 + lane]);

    const int j0 = (node == 0) ? 0 : (tmp[node - 1] + sbx[(node - 1) >> 8]);
    const int jend = tmp[node] + sbx[node >> 8];

    float l = 0.f, wacc = 0.f;
    float4 acc = make_float4(0.f, 0.f, 0.f, 0.f);

    const uint2 zkv = make_uint2(0u, 0u);
    uint2 kvA[4], kvB[4];
    float eaA[4], eaB[4];
    int2 idx[4];

    int j = j0;
    if (j < jend) {
        // group 0 data -> A (inline indices)
        #pragma unroll
        for (int i = 0; i < 4; i++) {
            if (j + i < jend) {
                int2 es = eid2[j + i];
                kvA[i] = *(const uint2*)(KV8 + (size_t)es.y * 512 + lane * 8);
                eaA[i] = EA[(size_t)es.x * 32 + hl];
            } else { kvA[i] = zkv; eaA[i] = 0.f; }
        }
        // indices for group 1
        ATTN_FETCHIDX(idx, j + 4);

        while (j < jend) {
            // phase A: data j+4 -> B, indices j+8, compute A(j)
            ATTN_LOADG(kvB, eaB, idx);
            ATTN_FETCHIDX(idx, j + 8);
            ATTN_COMPUTE(kvA, eaA, j);
            j += 4;
            if (j >= jend) break;

            // phase B: data j+4 -> A, indices j+8, compute B(j)
            ATTN_LOADG(kvA, eaA, idx);
            ATTN_FETCHIDX(idx, j + 8);
            ATTN_COMPUTE(kvB, eaB, j);
            j += 4;
        }
    }

    float r = 1.f / (l + 1e-16f);
    weab[(size_t)node * 64 + lane] = f2bf(wacc * r);
    float ax = acc.x * r, ay = acc.y * r, az = acc.z * r, aw = acc.w * r;
    float mx = 0.5f * (ax + __shfl_xor(ax, 32));
    float my = 0.5f * (ay + __shfl_xor(ay, 32));
    float mz = 0.5f * (az + __shfl_xor(az, 32));
    float mw = 0.5f * (aw + __shfl_xor(aw, 32));
    if (lane < 32)
        *(float4*)(agg + (size_t)node * 128 + hl * 4) = make_float4(mx, my, mz, mw);
}

// ---------------------------------------------------------------------------
extern "C" void kernel_launch(void* const* d_in, const int* in_sizes, int n_in,
                              void* d_out, int out_size, void* d_ws, size_t ws_size,
                              hipStream_t stream) {
    const float* x    = (const float*)d_in[0];
    const int*   ei   = (const int*)d_in[1];
    const float* ea   = (const float*)d_in[2];
    const float* Wq   = (const float*)d_in[3];
    const float* bq   = (const float*)d_in[4];
    const float* Wk   = (const float*)d_in[5];
    const float* bk   = (const float*)d_in[6];
    const float* Wv   = (const float*)d_in[7];
    const float* bv   = (const float*)d_in[8];
    const float* We   = (const float*)d_in[9];
    const float* Wsk  = (const float*)d_in[10];
    const float* bsk  = (const float*)d_in[11];
    const float* g1   = (const float*)d_in[12];
    const float* b1l  = (const float*)d_in[13];
    const float* W1   = (const float*)d_in[14];
    const float* b1f  = (const float*)d_in[15];
    const float* W2   = (const float*)d_in[16];
    const float* b2f  = (const float*)d_in[17];
    const float* g2   = (const float*)d_in[18];
    const float* b2l  = (const float*)d_in[19];
    float* out = (float*)d_out;

    const int N = in_sizes[0] / 128;
    const int E = in_sizes[2] / 32;
    const int* src = ei;
    const int* dst = ei + E;

    char* w = (char*)d_ws;
    unsigned short* O1   = (unsigned short*)w;  w += (size_t)N * 2048;  // [N,1024] bf16
    float* agg           = (float*)w;           w += (size_t)N * 512;   // [N,128] f32
    unsigned short* weab = (unsigned short*)w;  w += (size_t)N * 128;   // [N,64] bf16
    unsigned short* hb   = (unsigned short*)w;  w += (size_t)N * 256;   // [N,128] bf16
    unsigned char* kv8   = (unsigned char*)w;   w += (size_t)N * 512;   // [N,512] fp8
    unsigned short* Wcat = (unsigned short*)w;  w += 1024 * 128 * 2;
    float* bcat          = (float*)w;           w += 1024 * 4;
    unsigned short* W1h  = (unsigned short*)w;  w += 256 * 128 * 2;
    unsigned short* W2h  = (unsigned short*)w;  w += 128 * 256 * 2;
    unsigned short* Wec2 = (unsigned short*)w;  w += 128 * 64 * 2;
    int2* eid2           = (int2*)w;            w += (size_t)E * 8;
    int* deg  = (int*)w;            // [N] — zeroed by memset (with cnt)
    int* cnt  = deg + N;            // [N]
    int* tmp  = cnt + N;            // [N]
    int* bsum = tmp + N;            // <=1024 (read-only after scan_block)
    int* sbxg = bsum + 1024;        // <=1024 (exclusive scan, for attn)

    // aliases of agg (timeline-disjoint):
    //   xh  bf16 [N,128] (N*256 B) — written by prep cast, read by projection;
    //                                 dead once fused_attn writes agg.
    //   mid bf16 [N,256] (N*512 B) — written by FFN1 after econ consumed agg.
    unsigned short* xh  = (unsigned short*)agg;
    unsigned short* mid = (unsigned short*)agg;

    const int gy64 = (N + 63) / 64;
    const int nb   = (N + 255) / 256;

    // ---- zero deg+cnt, prep weights + deg_count + x-cast (one dispatch) ----
    hipMemsetAsync(deg, 0, (size_t)2 * N * 4, stream);
    const int total8 = (N * 128) / 8;
    prep_all<<<(WPREP + E + total8 + 255) / 256, 256, 0, stream>>>(
        Wq, bq, Wk, bk, Wv, bv, We, Wsk, bsk, W1, W2,
        Wcat, bcat, W1h, W2h, Wec2, dst, deg, E, x, xh, total8);

    // ---- projection GEMM (bf16 A, BM=64): O1 = xh @ Wcat^T + bcat ----
    gemm_fused<0,0,1><<<dim3(8, gy64), 256, 0, stream>>>(
        xh, 128, Wcat, 128, bcat, O1, 1024, N, 128,
        nullptr, nullptr, nullptr, 0, nullptr, nullptr, nullptr);

    // ---- CSR block scan ----
    scan_block<<<nb, 256, 0, stream>>>(deg, tmp, bsum, N);

    // ---- merged: csr_fill (local bsum scan, publishes sbxg) + cvt_kv ----
    const int totkv = N * 64;
    const int nbf = (E + 255) / 256;
    const int nbc = (totkv + 255) / 256;
    fill_cvt<<<nbf + nbc, 256, 0, stream>>>(
        src, dst, tmp, bsum, nb, sbxg, cnt, eid2, E, O1, kv8, totkv, nbf);

    // ---- attention (1 wave/block, 4-edge ping-pong, fp8 KV) ----
    fused_attn<<<N, 64, 0, stream>>>(O1, kv8, ea, tmp, sbxg, eid2, agg, weab, N);

    // ---- econ GEMM + LN1 fused: hb = LN1(weab@Wec2^T + agg + x + skip) ----
    gemm_fused<0,1,1><<<dim3(1, gy64), 256, 0, stream>>>(
        weab, 64, Wec2, 64, nullptr, hb, 128, N, 64,
        agg, x, O1 + 768, 1024, nullptr, g1, b1l);

    // ---- FFN1: mid = leaky(hb @ W1h^T + b1f) ----
    gemm_fused<1,0,1><<<dim3(2, gy64), 256, 0, stream>>>(
        hb, 128, W1h, 128, b1f, mid, 256, N, 128,
        nullptr, nullptr, nullptr, 0, nullptr, nullptr, nullptr);

    // ---- FFN2 + LN2 fused: out = LN2(hb + mid @ W2h^T + b2f) ----
    gemm_fused<0,2,0><<<dim3(1, gy64), 256, 0, stream>>>(
        mid, 256, W2h, 256, b2f, out, 128, N, 256,
        nullptr, nullptr, nullptr, 0, hb, g2, b2l);
}